// Round 1
// baseline (236.527 us; speedup 1.0000x reference)
//
#include <hip/hip_runtime.h>
#include <cmath>

#define N_NODES 30460
#define D 64
#define B 128
#define K_SEL 6924
#define S_TOT (B * K_SEL)      /* 886272 */
#define M_TOT (B * 50)         /* 6400 */
#define A_HID 20

// workspace layout (in floats)
#define WS_EXPB  0
#define WS_DENOM (WS_EXPB + M_TOT)      /* 6400  : [B] */
#define WS_ACC   (WS_DENOM + B)         /* 6528  : [B*D] */
#define WS_PORT  (WS_ACC + B * D)       /* 14720 : [B*D] */
#define WS_TW    (WS_PORT + B * D)      /* 22912 : [2*B] */

// ---- portrait stage 1: beta -> exp(beta) per mention ----
__global__ void k_beta(const float* __restrict__ graph, const float* __restrict__ Wa,
                       const float* __restrict__ Va, const int* __restrict__ midx,
                       float* __restrict__ expb) {
    __shared__ float sWa[D * A_HID];
    __shared__ float sVa[A_HID];
    int t = threadIdx.x;
    for (int i = t; i < D * A_HID; i += blockDim.x) sWa[i] = Wa[i];
    if (t < A_HID) sVa[t] = Va[t];
    __syncthreads();
    int m = blockIdx.x * blockDim.x + t;
    if (m >= M_TOT) return;
    int idx = midx[m];                         // mention_index in [0, N_NODES)
    const float* me = graph + (size_t)idx * D;
    float h[A_HID];
#pragma unroll
    for (int j = 0; j < A_HID; j++) h[j] = 0.f;
    for (int d = 0; d < D; d++) {
        float v = me[d];
#pragma unroll
        for (int j = 0; j < A_HID; j++) h[j] += v * sWa[d * A_HID + j];
    }
    float beta = 0.f;
#pragma unroll
    for (int j = 0; j < A_HID; j++) beta += tanhf(h[j]) * sVa[j];
    expb[m] = expf(beta);
}

// ---- portrait stage 2: atomic segment-sum of exp*me and exp ----
__global__ void k_scatter(const float* __restrict__ graph, const int* __restrict__ midx,
                          const int* __restrict__ mbat, const float* __restrict__ expb,
                          float* __restrict__ acc, float* __restrict__ denom) {
    int tid = blockIdx.x * blockDim.x + threadIdx.x;
    int m = tid >> 6, d = tid & 63;
    if (m >= M_TOT) return;
    float e = expb[m];
    int b = mbat[m];
    float v = graph[(size_t)midx[m] * D + d];
    atomicAdd(&acc[b * D + d], e * v);
    if (d == 0) atomicAdd(&denom[b], e);
}

// ---- portrait stage 3: normalize ----
__global__ void k_norm(const float* __restrict__ acc, const float* __restrict__ denom,
                       float* __restrict__ port) {
    int i = blockIdx.x * blockDim.x + threadIdx.x;
    if (i < B * D) port[i] = acc[i] / denom[i >> 6];
}

// ---- per-group gate tw for both layers ----
__global__ void k_tw(const float* __restrict__ graph, const float* __restrict__ abs_e,
                     const float* __restrict__ utter, const float* __restrict__ port,
                     const float* __restrict__ W1w, const float* __restrict__ W1b,
                     const float* __restrict__ W2w, const float* __restrict__ W2b,
                     const int* __restrict__ gb0, const int* __restrict__ la0, const int* __restrict__ it0,
                     const int* __restrict__ gb1, const int* __restrict__ la1, const int* __restrict__ it1,
                     float* __restrict__ tw) {
    int t = threadIdx.x;
    if (t >= 2 * B) return;
    int l = t >> 7, g = t & (B - 1);
    const int* gbp = l ? gb1 : gb0;
    const int* lsp = l ? la1 : la0;
    const int* itp = l ? it1 : it0;
    const float* Ww = l ? W2w : W1w;
    const float* Wb = l ? W2b : W1b;
    int gb = gbp[g], li = lsp[g], it = itp[g];
    const float* wr = Ww + it * 3 * D;         // row `it` of [3,192]
    float a = Wb[it];
    const float* u = utter + (size_t)gb * D;
    const float* p = port + (size_t)gb * D;
    const float* s = (li < N_NODES) ? (graph + (size_t)li * D) : abs_e;
    for (int k = 0; k < D; k++) a += u[k] * wr[k];
    for (int k = 0; k < D; k++) a += p[k] * wr[D + k];
    for (int k = 0; k < D; k++) a += s[k] * wr[2 * D + k];
    tw[l * B + g] = 1.f / (1.f + expf(-a));
}

// ---- main scoring: 16 lanes per output, coalesced row gather + shfl reduce ----
__global__ __launch_bounds__(256) void k_score(
    const float* __restrict__ graph, const float* __restrict__ abs_e,
    const float* __restrict__ utter, const float* __restrict__ port,
    const float* __restrict__ tw_ws,
    const int* __restrict__ si0, const int* __restrict__ sb0, const int* __restrict__ sg0,
    const int* __restrict__ si1, const int* __restrict__ sb1, const int* __restrict__ sg1,
    float* __restrict__ out) {
    const int layer = blockIdx.y;
    const int* __restrict__ si = layer ? si1 : si0;
    const int* __restrict__ sb = layer ? sb1 : sb0;
    const int* __restrict__ sg = layer ? sg1 : sg0;
    int s = blockIdx.x * 16 + (threadIdx.x >> 4);
    int sub = threadIdx.x & 15;

    int idx = si[s];
    int bat = sb[s];
    int grp = sg[s];
    float tw = tw_ws[layer * B + grp];
    float om = 1.f - tw;

    const float4* row = (const float4*)((idx < N_NODES) ? (graph + (size_t)idx * D) : abs_e);
    float4 g4 = row[sub];
    float4 u4 = ((const float4*)utter)[bat * 16 + sub];
    float4 p4 = ((const float4*)port)[bat * 16 + sub];

    float part = (u4.x * tw + p4.x * om) * g4.x
               + (u4.y * tw + p4.y * om) * g4.y
               + (u4.z * tw + p4.z * om) * g4.z
               + (u4.w * tw + p4.w * om) * g4.w;
    part += __shfl_xor(part, 8, 64);
    part += __shfl_xor(part, 4, 64);
    part += __shfl_xor(part, 2, 64);
    part += __shfl_xor(part, 1, 64);
    if (sub == 0) out[(size_t)layer * S_TOT + s] = part;
}

extern "C" void kernel_launch(void* const* d_in, const int* in_sizes, int n_in,
                              void* d_out, int out_size, void* d_ws, size_t ws_size,
                              hipStream_t stream) {
    const float* graph = (const float*)d_in[0];
    const float* utter = (const float*)d_in[1];
    const float* abs_e = (const float*)d_in[2];
    const float* Wa    = (const float*)d_in[3];
    const float* Va    = (const float*)d_in[4];
    const float* W1w   = (const float*)d_in[5];
    const float* W1b   = (const float*)d_in[6];
    const float* W2w   = (const float*)d_in[7];
    const float* W2b   = (const float*)d_in[8];
    const int* midx = (const int*)d_in[9];
    const int* mbat = (const int*)d_in[10];
    const int* si0 = (const int*)d_in[11];
    const int* sb0 = (const int*)d_in[12];
    const int* sg0 = (const int*)d_in[13];
    const int* gb0 = (const int*)d_in[14];
    const int* la0 = (const int*)d_in[15];
    const int* it0 = (const int*)d_in[16];
    const int* si1 = (const int*)d_in[17];
    const int* sb1 = (const int*)d_in[18];
    const int* sg1 = (const int*)d_in[19];
    const int* gb1 = (const int*)d_in[20];
    const int* la1 = (const int*)d_in[21];
    const int* it1 = (const int*)d_in[22];

    float* ws    = (float*)d_ws;
    float* expb  = ws + WS_EXPB;
    float* denom = ws + WS_DENOM;
    float* acc   = ws + WS_ACC;
    float* port  = ws + WS_PORT;
    float* tw    = ws + WS_TW;

    // zero the atomic accumulators (denom + acc are contiguous)
    hipMemsetAsync(denom, 0, (B + B * D) * sizeof(float), stream);

    k_beta<<<(M_TOT + 255) / 256, 256, 0, stream>>>(graph, Wa, Va, midx, expb);
    k_scatter<<<(M_TOT * 64 + 255) / 256, 256, 0, stream>>>(graph, midx, mbat, expb, acc, denom);
    k_norm<<<(B * D + 255) / 256, 256, 0, stream>>>(acc, denom, port);
    k_tw<<<1, 256, 0, stream>>>(graph, abs_e, utter, port, W1w, W1b, W2w, W2b,
                                gb0, la0, it0, gb1, la1, it1, tw);

    dim3 grid(S_TOT / 16, 2);   // 886272/16 = 55392 exactly
    k_score<<<grid, 256, 0, stream>>>(graph, abs_e, utter, port, tw,
                                      si0, sb0, sg0, si1, sb1, sg1, (float*)d_out);
}